// Round 2
// baseline (130.686 us; speedup 1.0000x reference)
//
#include <hip/hip_runtime.h>
#include <hip/hip_bf16.h>
#include <math.h>

// Problem constants
constexpr int NB    = 4;      // batch
constexpr int NHID  = 4096;
constexpr int NHEAD = 32;
constexpr int NKV   = 8;
constexpr int NGQ   = 4;      // heads per kv group
constexpr int ND    = 128;
constexpr int NS    = 16384;
constexpr int NPG   = 64;     // page size
constexpr int NP    = 256;    // num pages
constexpr int NTOP  = 64;
constexpr int NSPLIT = 32;    // flash-decode splits
constexpr int PPS   = NTOP / NSPLIT;  // pages per split = 2
constexpr float FSCALE = 0.08838834764831845f; // 1/sqrt(128)

constexpr int QKV_BLOCKS = 6144 / 4;   // 1536
constexpr int MM_BLOCKS  = NB * NKV * NP; // 8192

// ---------------------------------------------------------------------------
// K1 (fused): blocks [0,1536) = QKV GEMV (4 rows/block);
//             blocks [1536, 1536+8192) = per-page K min/max scan (float4).
// Both are HBM-bound streams; co-scheduling them in one launch keeps the
// memory system saturated and removes a serialization point (the scan does
// not depend on q).
// ---------------------------------------------------------------------------
__global__ __launch_bounds__(256) void k_qkv_minmax(
    const float* __restrict__ hs, const float* __restrict__ Wq,
    const float* __restrict__ Wk, const float* __restrict__ Wv,
    const float* __restrict__ kc, float* __restrict__ qkv,
    float* __restrict__ kmm) {
  int bid = blockIdx.x;
  int t = threadIdx.x;
  if (bid < QKV_BLOCKS) {
    // ---- QKV GEMV ----
    int row0 = bid * 4;
    const float4* x4 = (const float4*)hs;
    const float4* wr[4];
#pragma unroll
    for (int r = 0; r < 4; r++) {
      int row = row0 + r;
      const float* w;
      if (row < 4096)      w = Wq + (size_t)row * NHID;
      else if (row < 5120) w = Wk + (size_t)(row - 4096) * NHID;
      else                 w = Wv + (size_t)(row - 5120) * NHID;
      wr[r] = (const float4*)w;
    }
    float acc[4][4] = {};
    for (int j = t; j < NHID / 4; j += 256) {
      float4 x0 = x4[j], x1 = x4[1024 + j], x2 = x4[2048 + j], x3 = x4[3072 + j];
#pragma unroll
      for (int r = 0; r < 4; r++) {
        float4 w4 = wr[r][j];
        acc[r][0] += w4.x * x0.x + w4.y * x0.y + w4.z * x0.z + w4.w * x0.w;
        acc[r][1] += w4.x * x1.x + w4.y * x1.y + w4.z * x1.z + w4.w * x1.w;
        acc[r][2] += w4.x * x2.x + w4.y * x2.y + w4.z * x2.z + w4.w * x2.w;
        acc[r][3] += w4.x * x3.x + w4.y * x3.y + w4.z * x3.z + w4.w * x3.w;
      }
    }
    __shared__ float red[4][16];
    int lane = t & 63, wv = t >> 6;
#pragma unroll
    for (int r = 0; r < 4; r++)
#pragma unroll
      for (int b = 0; b < 4; b++) {
        float v = acc[r][b];
        v += __shfl_down(v, 32); v += __shfl_down(v, 16); v += __shfl_down(v, 8);
        v += __shfl_down(v, 4);  v += __shfl_down(v, 2);  v += __shfl_down(v, 1);
        if (lane == 0) red[wv][r * 4 + b] = v;
      }
    __syncthreads();
    if (t < 16) {
      int r = t >> 2, b = t & 3;
      float s = red[0][t] + red[1][t] + red[2][t] + red[3][t];
      qkv[(size_t)b * 6144 + row0 + r] = s;
    }
  } else {
    // ---- per-page min/max scan, float4 ----
    int pid = bid - QKV_BLOCKS;        // (b*8+kv)*256 + p
    const float4* Kp = (const float4*)(kc + (size_t)pid * NPG * ND);
    int c4 = t & 31, rg = t >> 5;      // 32 col-groups x 8 row-groups
    float4 mn = make_float4(INFINITY, INFINITY, INFINITY, INFINITY);
    float4 mx = make_float4(-INFINITY, -INFINITY, -INFINITY, -INFINITY);
#pragma unroll
    for (int r = 0; r < 8; r++) {
      float4 v = Kp[(rg * 8 + r) * 32 + c4];
      mn.x = fminf(mn.x, v.x); mn.y = fminf(mn.y, v.y);
      mn.z = fminf(mn.z, v.z); mn.w = fminf(mn.w, v.w);
      mx.x = fmaxf(mx.x, v.x); mx.y = fmaxf(mx.y, v.y);
      mx.z = fmaxf(mx.z, v.z); mx.w = fmaxf(mx.w, v.w);
    }
    __shared__ float4 smn[8][32], smx[8][32];
    smn[rg][c4] = mn; smx[rg][c4] = mx;
    __syncthreads();
    if (t < 32) {
      float4 a = smn[0][t], b4 = smx[0][t];
#pragma unroll
      for (int r = 1; r < 8; r++) {
        float4 u = smn[r][t], w = smx[r][t];
        a.x = fminf(a.x, u.x); a.y = fminf(a.y, u.y);
        a.z = fminf(a.z, u.z); a.w = fminf(a.w, u.w);
        b4.x = fmaxf(b4.x, w.x); b4.y = fmaxf(b4.y, w.y);
        b4.z = fmaxf(b4.z, w.z); b4.w = fmaxf(b4.w, w.w);
      }
      float4* dst = (float4*)kmm + (size_t)pid * 64;
      dst[t] = a;          // min[128]
      dst[32 + t] = b4;    // max[128]
    }
  }
}

// ---------------------------------------------------------------------------
// K2 (fused): RoPE(q, k_new) + v_new copy + group-mean qm (LDS only) +
// page scores from kmm + rank-based top-64. One block per (b,kv).
// ---------------------------------------------------------------------------
__global__ __launch_bounds__(256) void k_rope_score_topk(
    const float* __restrict__ qkv, const float* __restrict__ cosp,
    const float* __restrict__ sinp, const float* __restrict__ kmm,
    float* __restrict__ qr, float* __restrict__ kn, float* __restrict__ vn,
    int* __restrict__ sel) {
  int bh = blockIdx.x;               // b*8+kv
  int b = bh >> 3, kv = bh & 7;
  const float* cs = cosp + b * ND;
  const float* sn = sinp + b * ND;
  int t = threadIdx.x;
  int g = t >> 6, i = t & 63;
  __shared__ float sq[4][ND];
  __shared__ __align__(16) float qmS[ND];
  __shared__ float sc[NP];
  {
    int h = kv * NGQ + g;
    const float* q = qkv + (size_t)b * 6144 + h * ND;
    float x1 = q[i], x2 = q[i + 64];
    float o1 = x1 * cs[i] - x2 * sn[i];
    float o2 = x2 * cs[i + 64] + x1 * sn[i + 64];
    float* dst = qr + ((size_t)b * NHEAD + h) * ND;
    dst[i] = o1; dst[i + 64] = o2;
    sq[g][i] = o1; sq[g][i + 64] = o2;
  }
  if (t < 64) {
    const float* k = qkv + (size_t)b * 6144 + 4096 + kv * ND;
    float x1 = k[t], x2 = k[t + 64];
    float* dst = kn + (size_t)bh * ND;
    dst[t] = x1 * cs[t] - x2 * sn[t];
    dst[t + 64] = x2 * cs[t + 64] + x1 * sn[t + 64];
  }
  if (t < 128) {
    vn[(size_t)bh * ND + t] = qkv[(size_t)b * 6144 + 5120 + kv * ND + t];
  }
  __syncthreads();
  if (t < 128) {
    qmS[t] = 0.25f * (sq[0][t] + sq[1][t] + sq[2][t] + sq[3][t]);
  }
  __syncthreads();
  // ---- page scores: 4 threads per page, 4 rounds of 64 pages ----
#pragma unroll
  for (int rd = 0; rd < 4; rd++) {
    int p = (t >> 2) + rd * 64;
    int q = t & 3;
    const float4* mm = (const float4*)kmm + ((size_t)bh * NP + p) * 64;
    float s = 0.f;
#pragma unroll
    for (int j = 0; j < 8; j++) {
      float4 mn = mm[q * 8 + j];
      float4 mx = mm[32 + q * 8 + j];
      const float4 qv = *(const float4*)&qmS[q * 32 + j * 4];
      s += fmaxf(qv.x * mn.x, qv.x * mx.x);
      s += fmaxf(qv.y * mn.y, qv.y * mx.y);
      s += fmaxf(qv.z * mn.z, qv.z * mx.z);
      s += fmaxf(qv.w * mn.w, qv.w * mx.w);
    }
    s += __shfl_xor(s, 1); s += __shfl_xor(s, 2);
    if (q == 0) sc[p] = s;
  }
  __syncthreads();
  // ---- top-64 by rank counting (tie: lower index wins, = lax.top_k set) ----
  float mine = sc[t];
  int rank = 0;
  for (int j = 0; j < NP; j++) {
    float v = sc[j];
    rank += (v > mine) || (v == mine && j < t);
  }
  if (rank < NTOP) sel[(size_t)bh * NTOP + rank] = t;
}

// ---------------------------------------------------------------------------
// K3: flash-decode partials over selected pages. Grid = (b*8+kv)*NSPLIT+sp.
// 4 waves = 4 query heads of the group; half-wave per row, 32 lanes x float4.
// Softmax with fixed m=0 (|logit| small), partial = (sum_w, sum_w*V).
// ---------------------------------------------------------------------------
__global__ __launch_bounds__(256) void k_attn_part(
    const float* __restrict__ kc, const float* __restrict__ vc,
    const float* __restrict__ qr, const int* __restrict__ sel,
    float* __restrict__ part_l, float* __restrict__ part_o) {
  int idx = blockIdx.x;
  int sp = idx & (NSPLIT - 1);
  int bh = idx / NSPLIT;              // b*8+kv
  int b = bh >> 3, kv = bh & 7;
  int t = threadIdx.x;
  int g = t >> 6, lane = t & 63;
  int h = kv * NGQ + g;
  int half = lane >> 5;               // 0: even rows, 1: odd rows
  int li = lane & 31;                 // col block (4 floats)
  const float4* q4 = (const float4*)(qr + ((size_t)b * NHEAD + h) * ND);
  float4 qv = q4[li];
  float lsum = 0.f;
  float4 o = make_float4(0.f, 0.f, 0.f, 0.f);
#pragma unroll
  for (int pi = 0; pi < PPS; pi++) {
    int page = sel[(size_t)bh * NTOP + sp * PPS + pi];
    const float4* Kp = (const float4*)(kc + ((size_t)bh * NS + (size_t)page * NPG) * ND);
    const float4* Vp = (const float4*)(vc + ((size_t)bh * NS + (size_t)page * NPG) * ND);
    for (int r2 = 0; r2 < NPG / 2; r2++) {
      int r = r2 * 2 + half;
      float4 kk = Kp[r * 32 + li];
      float d = kk.x * qv.x + kk.y * qv.y + kk.z * qv.z + kk.w * qv.w;
      d += __shfl_xor(d, 1); d += __shfl_xor(d, 2); d += __shfl_xor(d, 4);
      d += __shfl_xor(d, 8); d += __shfl_xor(d, 16);
      float w = __expf(d * FSCALE);
      lsum += w;
      float4 vv = Vp[r * 32 + li];
      o.x += w * vv.x; o.y += w * vv.y; o.z += w * vv.z; o.w += w * vv.w;
    }
  }
  o.x += __shfl_xor(o.x, 32); o.y += __shfl_xor(o.y, 32);
  o.z += __shfl_xor(o.z, 32); o.w += __shfl_xor(o.w, 32);
  lsum += __shfl_xor(lsum, 32);
  if (half == 0) {
    float4* po = (float4*)(part_o + (((size_t)bh * NGQ + g) * NSPLIT + sp) * ND);
    po[li] = o;
    if (li == 0) part_l[((size_t)bh * NGQ + g) * NSPLIT + sp] = lsum;
  }
}

// ---------------------------------------------------------------------------
// K4: combine partials + the appended (k_new, v_new) row; normalize.
// ---------------------------------------------------------------------------
__global__ __launch_bounds__(64) void k_combine(
    const float* __restrict__ qr, const float* __restrict__ kn,
    const float* __restrict__ vn, const float* __restrict__ part_l,
    const float* __restrict__ part_o, float* __restrict__ attno) {
  int bid = blockIdx.x;                // b*32 + h
  int b = bid >> 5, h = bid & 31;
  int kv = h >> 2, g = h & 3;
  int lane = threadIdx.x;
  int bh = b * NKV + kv;
  const float2* q2 = (const float2*)(qr + ((size_t)b * NHEAD + h) * ND);
  const float2* k2 = (const float2*)(kn + (size_t)bh * ND);
  float2 qv = q2[lane], kk = k2[lane];
  float d = qv.x * kk.x + qv.y * kk.y;
  d += __shfl_xor(d, 1); d += __shfl_xor(d, 2); d += __shfl_xor(d, 4);
  d += __shfl_xor(d, 8); d += __shfl_xor(d, 16); d += __shfl_xor(d, 32);
  float wn = __expf(d * FSCALE);
  const float2* v2 = (const float2*)(vn + (size_t)bh * ND);
  float2 vv = v2[lane];
  float ox = wn * vv.x, oy = wn * vv.y, lt = wn;
  const float* pl = part_l + ((size_t)bh * NGQ + g) * NSPLIT;
  const float2* po = (const float2*)(part_o + (((size_t)bh * NGQ + g) * NSPLIT) * ND);
  for (int s = 0; s < NSPLIT; s++) {
    lt += pl[s];
    float2 p = po[(size_t)s * 64 + lane];
    ox += p.x; oy += p.y;
  }
  float inv = 1.0f / lt;
  float2* ao = (float2*)(attno + ((size_t)b * NHEAD + h) * ND);
  ao[lane] = make_float2(ox * inv, oy * inv);
}

// ---------------------------------------------------------------------------
// K5: output projection. out[b*4096+row] = dot(Wo[row], attno[b]).
// ---------------------------------------------------------------------------
__global__ __launch_bounds__(256) void k_oproj(
    const float* __restrict__ Wo, const float* __restrict__ x,
    float* __restrict__ out) {
  int row0 = blockIdx.x * 4;
  int t = threadIdx.x;
  const float4* x4 = (const float4*)x;
  float acc[4][4] = {};
  for (int j = t; j < NHID / 4; j += 256) {
    float4 x0 = x4[j], x1 = x4[1024 + j], x2 = x4[2048 + j], x3 = x4[3072 + j];
#pragma unroll
    for (int r = 0; r < 4; r++) {
      float4 w4 = ((const float4*)(Wo + (size_t)(row0 + r) * NHID))[j];
      acc[r][0] += w4.x * x0.x + w4.y * x0.y + w4.z * x0.z + w4.w * x0.w;
      acc[r][1] += w4.x * x1.x + w4.y * x1.y + w4.z * x1.z + w4.w * x1.w;
      acc[r][2] += w4.x * x2.x + w4.y * x2.y + w4.z * x2.z + w4.w * x2.w;
      acc[r][3] += w4.x * x3.x + w4.y * x3.y + w4.z * x3.z + w4.w * x3.w;
    }
  }
  __shared__ float red[4][16];
  int lane = t & 63, wv = t >> 6;
#pragma unroll
  for (int r = 0; r < 4; r++)
#pragma unroll
    for (int b = 0; b < 4; b++) {
      float v = acc[r][b];
      v += __shfl_down(v, 32); v += __shfl_down(v, 16); v += __shfl_down(v, 8);
      v += __shfl_down(v, 4);  v += __shfl_down(v, 2);  v += __shfl_down(v, 1);
      if (lane == 0) red[wv][r * 4 + b] = v;
    }
  __syncthreads();
  if (t < 16) {
    int r = t >> 2, b = t & 3;
    float s = red[0][t] + red[1][t] + red[2][t] + red[3][t];
    out[(size_t)b * NHID + row0 + r] = s;
  }
}

// ---------------------------------------------------------------------------
extern "C" void kernel_launch(void* const* d_in, const int* in_sizes, int n_in,
                              void* d_out, int out_size, void* d_ws, size_t ws_size,
                              hipStream_t stream) {
  const float* hs   = (const float*)d_in[0];
  const float* cosp = (const float*)d_in[1];
  const float* sinp = (const float*)d_in[2];
  const float* kc   = (const float*)d_in[3];
  const float* vc   = (const float*)d_in[4];
  const float* Wq   = (const float*)d_in[5];
  const float* Wk   = (const float*)d_in[6];
  const float* Wv   = (const float*)d_in[7];
  const float* Wo   = (const float*)d_in[8];
  float* out = (float*)d_out;

  float* ws = (float*)d_ws;
  float* qkv    = ws;                      // 24576 floats
  float* qr     = ws + 24576;              // 16384
  float* kn     = ws + 40960;              // 4096
  float* vn     = ws + 45056;              // 4096
  float* kmm    = ws + 49152;              // 32*256*256 = 2097152
  int*   sel    = (int*)(ws + 2146304);    // 2048 ints
  float* part_l = ws + 2148352;            // 4096
  float* part_o = ws + 2152448;            // 524288
  float* attno  = ws + 2676736;            // 16384

  k_qkv_minmax<<<QKV_BLOCKS + MM_BLOCKS, 256, 0, stream>>>(hs, Wq, Wk, Wv, kc, qkv, kmm);
  k_rope_score_topk<<<NB * NKV, 256, 0, stream>>>(qkv, cosp, sinp, kmm, qr, kn, vn, sel);
  k_attn_part<<<NB * NKV * NSPLIT, 256, 0, stream>>>(kc, vc, qr, sel, part_l, part_o);
  k_combine<<<NB * NHEAD, 64, 0, stream>>>(qr, kn, vn, part_l, part_o, attno);
  k_oproj<<<NHID / 4, 256, 0, stream>>>(Wo, attno, out);
}